// Round 13
// baseline (192.496 us; speedup 1.0000x reference)
//
#include <hip/hip_runtime.h>
#include <hip/hip_bf16.h>
#include <math.h>

// Problem constants
#define DIMC   256      // DIM
#define DI     512      // D_INNER
#define DS     16       // D_STATE
#define DTR    16       // DT_RANK
#define NX     48       // DT_RANK + 2*D_STATE
#define BATCH  8
#define LSEQ   1024     // H*W
#define MROWS  8192     // BATCH*LSEQ
#define CHUNK  64
#define NC     (LSEQ / CHUNK)   // 16 chunks

typedef __attribute__((ext_vector_type(8))) short short8;
typedef __attribute__((ext_vector_type(4))) float f32x4;

__device__ __forceinline__ unsigned short f2bf(float v) {
  __hip_bfloat16 h = __float2bfloat16(v);
  return *reinterpret_cast<unsigned short*>(&h);
}
__device__ __forceinline__ float bf2f(unsigned short u) {
  return __int_as_float(((int)u) << 16);
}

// Sum across the 16-lane group using DPP only (zero DS ops).
__device__ __forceinline__ float dpp_sum16(float v) {
  float t;
  t = __int_as_float(__builtin_amdgcn_mov_dpp(__float_as_int(v), 0xB1,  0xF, 0xF, true)); v += t; // ^1
  t = __int_as_float(__builtin_amdgcn_mov_dpp(__float_as_int(v), 0x4E,  0xF, 0xF, true)); v += t; // ^2
  t = __int_as_float(__builtin_amdgcn_mov_dpp(__float_as_int(v), 0x141, 0xF, 0xF, true)); v += t; // ^7 (row_half_mirror)
  t = __int_as_float(__builtin_amdgcn_mov_dpp(__float_as_int(v), 0x140, 0xF, 0xF, true)); v += t; // ^15 (row_mirror)
  return v;
}

// ---------------------------------------------------------------------------
// Prologue: weight prep + LayerNorm in ONE launch (branch on blockIdx.x).
__global__ __launch_bounds__(256) void prologue(const float* __restrict__ W_in,
                                                const float* __restrict__ W_out,
                                                const float* __restrict__ W_xproj,
                                                const float* __restrict__ W_dt,
                                                const float* __restrict__ x,
                                                const float* __restrict__ gamma,
                                                const float* __restrict__ beta,
                                                unsigned short* __restrict__ Wib,
                                                unsigned short* __restrict__ Wob,
                                                unsigned short* __restrict__ Wxpb,
                                                unsigned short* __restrict__ Wdtb,
                                                unsigned short* __restrict__ xnb) {
  __shared__ float sx[DIMC][67];
  __shared__ float smean[64], srs[64];
  const int blk = blockIdx.x, tid = threadIdx.x;
  if (blk < 384) {
    float (*t)[67] = sx;
    const float* W; unsigned short* Wt; int K, N, bx, by;
    if (blk < 256) { W = W_in;  Wt = Wib; K = DIMC; N = 1024; bx = blk & 31; by = blk >> 5; }
    else           { W = W_out; Wt = Wob; K = DI;   N = DIMC; bx = (blk - 256) & 7; by = (blk - 256) >> 3; }
    int n0 = bx * 32, k0 = by * 32;
    int tx = tid & 31, ty = tid >> 5;
    for (int i = ty; i < 32; i += 8) t[i][tx] = W[(size_t)(k0 + i) * N + n0 + tx];
    __syncthreads();
    for (int i = ty; i < 32; i += 8)
      Wt[(size_t)(n0 + i) * K + k0 + tx] = f2bf(t[tx][i]);
    return;
  }
  if (blk < 512) {
    int idx = (blk - 384) * 256 + tid;   // < 64*512
    int n = idx >> 9, k = idx & 511;
    Wxpb[idx] = (n < NX) ? f2bf(W_xproj[(size_t)k * NX + n]) : (unsigned short)0;
    return;
  }
  if (blk < 576) {
    int idx = (blk - 512) * 256 + tid;   // < 512*32
    int n = idx >> 5, k = idx & 31;
    Wdtb[idx] = (k < DTR) ? f2bf(W_dt[(size_t)k * DI + n]) : (unsigned short)0;
    return;
  }
  // ---- LayerNorm ----
  const int lb = blk - 576;
  const int b = lb >> 4, l0 = (lb & 15) * 64;
  {
    const int cbase = tid >> 2;
    const int lp = (tid & 3) * 16;
#pragma unroll
    for (int cg = 0; cg < 4; ++cg) {
      const int c = cg * 64 + cbase;
      const float* p = x + ((size_t)b * DIMC + c) * LSEQ + l0 + lp;
#pragma unroll
      for (int q = 0; q < 4; ++q) {
        float4 v = *(const float4*)(p + q * 4);
        sx[c][lp + q * 4 + 0] = v.x;
        sx[c][lp + q * 4 + 1] = v.y;
        sx[c][lp + q * 4 + 2] = v.z;
        sx[c][lp + q * 4 + 3] = v.w;
      }
    }
  }
  __syncthreads();
  {
    const int lane = tid & 63, w = tid >> 6;
    const int l = (w << 4) + (lane & 15);
    const int quad = lane >> 4;
    float sum = 0.f, sq = 0.f;
#pragma unroll 8
    for (int cc = 0; cc < 64; ++cc) {
      float v = sx[quad * 64 + cc][l];
      sum += v; sq += v * v;
    }
    sum += __shfl_xor(sum, 16); sq += __shfl_xor(sq, 16);
    sum += __shfl_xor(sum, 32); sq += __shfl_xor(sq, 32);
    if (quad == 0) {
      float mean = sum * (1.f / 256.f);
      float var  = sq * (1.f / 256.f) - mean * mean;
      smean[l] = mean; srs[l] = rsqrtf(var + 1e-5f);
    }
  }
  __syncthreads();
  {
    const float gg = gamma[tid], bb = beta[tid];
    const size_t base = ((size_t)b * LSEQ + l0) * DIMC + tid;
#pragma unroll 4
    for (int ll = 0; ll < 64; ++ll) {
      float v = (sx[tid][ll] - smean[ll]) * srs[ll] * gg + bb;
      xnb[base + (size_t)ll * DIMC] = f2bf(v);
    }
  }
}

// ---------------------------------------------------------------------------
// bf16 MFMA GEMM: C = A(bf16 [M][K]) * Bt(bf16 [N][K])^T.
// mode 1: f32 out[b*DIMC*LSEQ + n*LSEQ + l] = acc + X  (transpose + residual)
// mode 2: bf16 C row-major [M][N]
#define GTM 128
#define GTN 64
#define GBK 32
__global__ __launch_bounds__(256) void gemm_bf16(const unsigned short* __restrict__ A,
                                                 const unsigned short* __restrict__ Bt,
                                                 void* __restrict__ Cout,
                                                 int M, int N, int K, int mode,
                                                 const float* __restrict__ X) {
  __shared__ unsigned short As[GTM][GBK];
  __shared__ unsigned short Bs[GTN][GBK];
  const int tid = threadIdx.x;
  const int lane = tid & 63, wave = tid >> 6;
  const int wm = wave >> 1, wn = wave & 1;
  const int quad = lane >> 4, l16 = lane & 15;
  const int m0 = blockIdx.y * GTM, n0 = blockIdx.x * GTN;

  f32x4 acc[4][2];
#pragma unroll
  for (int i = 0; i < 4; ++i)
#pragma unroll
    for (int j = 0; j < 2; ++j) acc[i][j] = (f32x4){0.f, 0.f, 0.f, 0.f};

  for (int k0 = 0; k0 < K; k0 += GBK) {
#pragma unroll
    for (int q = 0; q < 2; ++q) {
      int id = q * 256 + tid;
      int row = id >> 2, c = id & 3;
      uint4 v = *(const uint4*)(A + (size_t)(m0 + row) * K + k0 + c * 8);
      *(uint4*)&As[row][c * 8] = v;
    }
    {
      int row = tid >> 2, c = tid & 3;
      uint4 v = *(const uint4*)(Bt + (size_t)(n0 + row) * K + k0 + c * 8);
      *(uint4*)&Bs[row][c * 8] = v;
    }
    __syncthreads();
    short8 af[4], bfrag[2];
#pragma unroll
    for (int i = 0; i < 4; ++i)
      af[i] = *(const short8*)&As[wm * 64 + i * 16 + l16][quad * 8];
#pragma unroll
    for (int j = 0; j < 2; ++j)
      bfrag[j] = *(const short8*)&Bs[wn * 32 + j * 16 + l16][quad * 8];
#pragma unroll
    for (int i = 0; i < 4; ++i)
#pragma unroll
      for (int j = 0; j < 2; ++j)
        acc[i][j] = __builtin_amdgcn_mfma_f32_16x16x32_bf16(af[i], bfrag[j], acc[i][j], 0, 0, 0);
    __syncthreads();
  }

  if (mode == 2) {
    unsigned short* Cb = (unsigned short*)Cout;
#pragma unroll
    for (int i = 0; i < 4; ++i) {
      int rowb = wm * 64 + i * 16 + quad * 4;
#pragma unroll
      for (int j = 0; j < 2; ++j) {
        int n = n0 + wn * 32 + j * 16 + l16;
#pragma unroll
        for (int r = 0; r < 4; ++r)
          Cb[(size_t)(m0 + rowb + r) * N + n] = f2bf(acc[i][j][r]);
      }
    }
  } else {
    float* C = (float*)Cout;
#pragma unroll
    for (int i = 0; i < 4; ++i) {
      int m = m0 + wm * 64 + i * 16 + quad * 4;
      int b = m >> 10, l = m & 1023;
#pragma unroll
      for (int j = 0; j < 2; ++j) {
        int n = n0 + wn * 32 + j * 16 + l16;
        size_t o = (size_t)b * (DIMC * LSEQ) + (size_t)n * LSEQ + l;
        f32x4 xv = *(const f32x4*)(X + o);
        f32x4 rv = acc[i][j] + xv;
        *(f32x4*)(C + o) = rv;
      }
    }
  }
}

// ---------------------------------------------------------------------------
// Fused conv + SiLU + xproj + dt (MFMA). m-tile 32, grid 256.
// Stages the 35x512 xz u-half tile (3-row causal halo), computes u in LDS,
// then: dbcBC[M][32] = (B|C) cols of u @ Wxpb^T; dtu = packed(bf16 dt, bf16 u).
__global__ __launch_bounds__(256) void conv_xproj_dt(
    const unsigned short* __restrict__ xzb,
    const float* __restrict__ conv_w,
    const float* __restrict__ conv_b,
    const unsigned short* __restrict__ Wxpb,
    const unsigned short* __restrict__ Wdtb,
    const float* __restrict__ b_dt,
    float* __restrict__ dbcBC,
    unsigned int* __restrict__ dtu) {
  __shared__ unsigned short Bs[64][512 + 8];
  __shared__ unsigned short sxz[35][512];
  __shared__ unsigned short su[32][512 + 8];
  __shared__ unsigned short sdbc[32][40];
  const int m0 = blockIdx.x * 32;
  const int l0 = m0 & 1023;
  const int tid = threadIdx.x, lane = tid & 63, w = tid >> 6;
  const int quad = lane >> 4, l16 = lane & 15;

  // Stage Wxpb (64x512) and the xz u-half tile with halo.
#pragma unroll
  for (int q = 0; q < 16; ++q) {
    int id = q * 256 + tid;
    int row = id >> 6, c8 = id & 63;
    *(uint4*)&Bs[row][c8 * 8] = *(const uint4*)(Wxpb + (size_t)row * 512 + c8 * 8);
  }
#pragma unroll
  for (int q = 0; q < 9; ++q) {
    int id = q * 256 + tid;           // < 35*64 = 2240 chunks
    if (id < 35 * 64) {
      int rr = id >> 6, c8 = id & 63;
      uint4 v; v.x = 0u; v.y = 0u; v.z = 0u; v.w = 0u;
      if (l0 - 3 + rr >= 0)
        v = *(const uint4*)(xzb + (size_t)(m0 - 3 + rr) * 1024 + c8 * 8);
      *(uint4*)&sxz[rr][c8 * 8] = v;
    }
  }
  __syncthreads();

  // conv(k=4) + bias + SiLU -> su (each thread 64 outputs, coalesced in c).
#pragma unroll 4
  for (int q = 0; q < 64; ++q) {
    int idx = q * 256 + tid;
    int r = idx >> 9, c = idx & 511;
    float4 wv = *(const float4*)(conv_w + c * 4);
    float acc = conv_b[c];
    acc = fmaf(bf2f(sxz[r + 0][c]), wv.x, acc);
    acc = fmaf(bf2f(sxz[r + 1][c]), wv.y, acc);
    acc = fmaf(bf2f(sxz[r + 2][c]), wv.z, acc);
    acc = fmaf(bf2f(sxz[r + 3][c]), wv.w, acc);
    float u = acc / (1.f + __expf(-acc));
    su[r][c] = f2bf(u);
  }
  __syncthreads();

  // xproj MFMA: A-frags straight from su.
  f32x4 acc[2];
  acc[0] = (f32x4){0.f, 0.f, 0.f, 0.f};
  acc[1] = (f32x4){0.f, 0.f, 0.f, 0.f};
#pragma unroll 4
  for (int k0 = 0; k0 < 512; k0 += 32) {
    short8 af0 = *(const short8*)&su[l16][k0 + quad * 8];
    short8 af1 = *(const short8*)&su[16 + l16][k0 + quad * 8];
    short8 bf  = *(const short8*)&Bs[w * 16 + l16][k0 + quad * 8];
    acc[0] = __builtin_amdgcn_mfma_f32_16x16x32_bf16(af0, bf, acc[0], 0, 0, 0);
    acc[1] = __builtin_amdgcn_mfma_f32_16x16x32_bf16(af1, bf, acc[1], 0, 0, 0);
  }
  // Persist only B (n=16..31) and C (n=32..47) columns.
  if (w == 1 || w == 2) {
#pragma unroll
    for (int i = 0; i < 2; ++i)
#pragma unroll
      for (int r = 0; r < 4; ++r)
        dbcBC[(size_t)(m0 + i * 16 + quad * 4 + r) * 32 + (w - 1) * 16 + l16] = acc[i][r];
  }
  if (w < 2) {
#pragma unroll
    for (int i = 0; i < 2; ++i)
#pragma unroll
      for (int r = 0; r < 4; ++r)
        sdbc[i * 16 + quad * 4 + r][w * 16 + l16] = f2bf(acc[i][r]);
  }
  __syncthreads();

  // dt MFMA + softplus + dtu pack (u pulled from su).
  short8 af0 = *(const short8*)&sdbc[l16][quad * 8];
  short8 af1 = *(const short8*)&sdbc[16 + l16][quad * 8];
#pragma unroll
  for (int jn = 0; jn < 8; ++jn) {
    const int n0 = w * 128 + jn * 16;
    short8 bf = *(const short8*)(Wdtb + (size_t)(n0 + l16) * 32 + quad * 8);
    f32x4 a0 = (f32x4){0.f, 0.f, 0.f, 0.f}, a1 = a0;
    a0 = __builtin_amdgcn_mfma_f32_16x16x32_bf16(af0, bf, a0, 0, 0, 0);
    a1 = __builtin_amdgcn_mfma_f32_16x16x32_bf16(af1, bf, a1, 0, 0, 0);
    const float bd = b_dt[n0 + l16];
#pragma unroll
    for (int r = 0; r < 4; ++r) {
      int lr0 = quad * 4 + r;
      int lr1 = lr0 + 16;
      float v = a0[r] + bd;
      float sp = (v > 20.f) ? v : log1pf(__expf(v));
      unsigned int u0 = (unsigned int)su[lr0][n0 + l16];
      dtu[(size_t)(m0 + lr0) * DI + n0 + l16] = u0 | ((unsigned int)f2bf(sp) << 16);
      float v2 = a1[r] + bd;
      float sp2 = (v2 > 20.f) ? v2 : log1pf(__expf(v2));
      unsigned int u1 = (unsigned int)su[lr1][n0 + l16];
      dtu[(size_t)(m0 + lr1) * DI + n0 + l16] = u1 | ((unsigned int)f2bf(sp2) << 16);
    }
  }
}

// ---------------------------------------------------------------------------
// Chunked selective scan, (d,s) LDS-staged layout.
// Pass 1: local scan from h=0 -> hend, sum dt. Grid (BATCH, 32, NC).
__global__ __launch_bounds__(256) void scan_pass1(const unsigned int* __restrict__ dtu,
                                                  const float* __restrict__ dbcBC,
                                                  const float* __restrict__ A_log,
                                                  float* __restrict__ hend,
                                                  float* __restrict__ Ssum) {
  const int bb = blockIdx.x, dblk = blockIdx.y, cc = blockIdx.z;
  const int tid = threadIdx.x;
  const int di = tid >> 4, s = tid & 15;
  const int d = dblk * 16 + di;
  const float Ads = -__expf(A_log[d * DS + s]);

  __shared__ float2 sdu[CHUNK][18];   // (dt, u); pad -> <=2-way on b128 writes
  __shared__ float  sB[CHUNK][17];
  {
    const int t0 = cc * CHUNK;
    int lin = tid * 4;                 // 4 elems per thread
    int tt = lin >> 4, dd = lin & 15;  // dd in {0,4,8,12}
    size_t m = (size_t)bb * LSEQ + t0 + tt;
    uint4 du4 = *(const uint4*)(dtu + m * DI + dblk * 16 + dd);
    f32x4 a, b2;
    a[0]  = bf2f((unsigned short)(du4.x >> 16)); a[1]  = bf2f((unsigned short)(du4.x & 0xffff));
    a[2]  = bf2f((unsigned short)(du4.y >> 16)); a[3]  = bf2f((unsigned short)(du4.y & 0xffff));
    b2[0] = bf2f((unsigned short)(du4.z >> 16)); b2[1] = bf2f((unsigned short)(du4.z & 0xffff));
    b2[2] = bf2f((unsigned short)(du4.w >> 16)); b2[3] = bf2f((unsigned short)(du4.w & 0xffff));
    *(f32x4*)&sdu[tt][dd]     = a;
    *(f32x4*)&sdu[tt][dd + 2] = b2;
    f32x4 Bv = *(const f32x4*)(dbcBC + m * 32 + dd);
    *(f32x4*)&sB[tt][dd] = Bv;
  }
  __syncthreads();
  float h = 0.f, dtsum = 0.f;
#pragma unroll 4
  for (int tt = 0; tt < CHUNK; ++tt) {
    float2 du = sdu[tt][di];
    float Bv  = sB[tt][s];
    h = fmaf(__expf(du.x * Ads), h, du.x * du.y * Bv);
    dtsum += du.x;
  }
  size_t ci = ((size_t)(bb * NC + cc) * DI + d);
  hend[ci * DS + s] = h;
  if (s == 0) Ssum[ci] = dtsum;
}

// Pass 2: sequential combine over chunks -> h_in per chunk. (tiny, 256 blocks)
__global__ __launch_bounds__(256) void scan_pass2(const float* __restrict__ A_log,
                                                  const float* __restrict__ hend,
                                                  const float* __restrict__ Ssum,
                                                  float* __restrict__ hin) {
  const int bb = blockIdx.x, dblk = blockIdx.y;
  const int tid = threadIdx.x;
  const int di = tid >> 4, s = tid & 15;
  const int d = dblk * 16 + di;
  const float Ads = -__expf(A_log[d * DS + s]);
  float h = 0.f;
  for (int cc = 0; cc < NC; ++cc) {
    size_t ci = ((size_t)(bb * NC + cc) * DI + d);
    hin[ci * DS + s] = h;
    h = fmaf(__expf(Ads * Ssum[ci]), h, hend[ci * DS + s]);
  }
}

// Pass 3: re-run each chunk from true h_in, fused gate epilogue -> yb (bf16).
__global__ __launch_bounds__(256) void scan_pass3(const unsigned int* __restrict__ dtu,
                                                  const float* __restrict__ dbcBC,
                                                  const unsigned short* __restrict__ xzb,
                                                  const float* __restrict__ A_log,
                                                  const float* __restrict__ D_skip,
                                                  const float* __restrict__ hin,
                                                  unsigned short* __restrict__ yb) {
  const int bb = blockIdx.x, dblk = blockIdx.y, cc = blockIdx.z;
  const int tid = threadIdx.x;
  const int di = tid >> 4, s = tid & 15;
  const int d = dblk * 16 + di;
  const float Ads = -__expf(A_log[d * DS + s]);

  __shared__ float2 sdu[CHUNK][18];   // (dt, u)
  __shared__ float2 sBC[CHUNK][18];   // (B, C)
  __shared__ float  sy[CHUNK][16];
  const int t0 = cc * CHUNK;
  const size_t mbase = (size_t)bb * LSEQ + t0;
  {
    int lin = tid * 4;
    int tt = lin >> 4, dd = lin & 15;   // dd in {0,4,8,12}
    size_t m = mbase + tt;
    uint4 du4 = *(const uint4*)(dtu + m * DI + dblk * 16 + dd);
    f32x4 a, b2;
    a[0]  = bf2f((unsigned short)(du4.x >> 16)); a[1]  = bf2f((unsigned short)(du4.x & 0xffff));
    a[2]  = bf2f((unsigned short)(du4.y >> 16)); a[3]  = bf2f((unsigned short)(du4.y & 0xffff));
    b2[0] = bf2f((unsigned short)(du4.z >> 16)); b2[1] = bf2f((unsigned short)(du4.z & 0xffff));
    b2[2] = bf2f((unsigned short)(du4.w >> 16)); b2[3] = bf2f((unsigned short)(du4.w & 0xffff));
    *(f32x4*)&sdu[tt][dd]     = a;
    *(f32x4*)&sdu[tt][dd + 2] = b2;
    f32x4 Bv = *(const f32x4*)(dbcBC + m * 32 + dd);
    f32x4 Cv = *(const f32x4*)(dbcBC + m * 32 + 16 + dd);
    f32x4 p0, p1;
    p0[0] = Bv[0]; p0[1] = Cv[0]; p0[2] = Bv[1]; p0[3] = Cv[1];
    p1[0] = Bv[2]; p1[1] = Cv[2]; p1[2] = Bv[3]; p1[3] = Cv[3];
    *(f32x4*)&sBC[tt][dd]     = p0;
    *(f32x4*)&sBC[tt][dd + 2] = p1;
  }
  __syncthreads();
  float h = hin[((size_t)(bb * NC + cc) * DI + d) * DS + s];
#pragma unroll 4
  for (int tt = 0; tt < CHUNK; ++tt) {
    float2 du = sdu[tt][di];
    float2 bc = sBC[tt][s];
    h = fmaf(__expf(du.x * Ads), h, du.x * du.y * bc.x);
    float v = dpp_sum16(h * bc.y);
    if (s == 0) sy[tt][di] = v;
  }
  __syncthreads();
#pragma unroll
  for (int q = 0; q < 4; ++q) {
    int lin = q * 256 + tid;
    int tt = lin >> 4, dd = lin & 15;
    size_t m = mbase + tt;
    float z = bf2f(xzb[m * 1024 + DI + dblk * 16 + dd]);   // direct global, coalesced
    float yv = sy[tt][dd] + sdu[tt][dd].y * D_skip[dblk * 16 + dd];
    yv *= z / (1.f + __expf(-z));
    yb[m * DI + dblk * 16 + dd] = f2bf(yv);
  }
}

// ---------------------------------------------------------------------------
extern "C" void kernel_launch(void* const* d_in, const int* in_sizes, int n_in,
                              void* d_out, int out_size, void* d_ws, size_t ws_size,
                              hipStream_t stream) {
  const float* x       = (const float*)d_in[0];
  const float* ln_g    = (const float*)d_in[1];
  const float* ln_b    = (const float*)d_in[2];
  const float* W_in    = (const float*)d_in[3];
  const float* conv_w  = (const float*)d_in[4];
  const float* conv_b  = (const float*)d_in[5];
  const float* W_xproj = (const float*)d_in[6];
  const float* W_dt    = (const float*)d_in[7];
  const float* b_dt    = (const float*)d_in[8];
  const float* A_log   = (const float*)d_in[9];
  const float* D_skip  = (const float*)d_in[10];
  const float* W_out   = (const float*)d_in[11];
  float* out = (float*)d_out;

  // Workspace layout
  float* ws    = (float*)d_ws;
  float* dbcBC = ws;                                    //   262,144 f
  float* hend  = dbcBC + (size_t)MROWS * 32;            // 1,048,576 f
  float* hin   = hend + (size_t)BATCH * NC * DI * DS;   // 1,048,576 f
  float* Ssum  = hin  + (size_t)BATCH * NC * DI * DS;   //    65,536 f
  unsigned int* dtu = (unsigned int*)(Ssum + (size_t)BATCH * NC * DI); // 4,194,304 u32
  unsigned short* xzb  = (unsigned short*)(dtu + (size_t)MROWS * DI); // 8,388,608 us
  unsigned short* yb   = xzb + (size_t)MROWS * 1024;    // 4,194,304 us
  unsigned short* xnb  = yb;   // alias: xnb dead before pass3 writes yb
  unsigned short* Wib  = yb  + (size_t)MROWS * DI;      // 262,144 us
  unsigned short* Wob  = Wib + (size_t)DIMC * 1024;     // 131,072 us
  unsigned short* Wxpb = Wob + (size_t)DI * DIMC;       //  32,768 us
  unsigned short* Wdtb = Wxpb + (size_t)64 * 512;       //  16,384 us

  // 0. prologue: weight prep + LayerNorm, one launch
  prologue<<<704, 256, 0, stream>>>(W_in, W_out, W_xproj, W_dt, x, ln_g, ln_b,
                                    Wib, Wob, Wxpb, Wdtb, xnb);

  // 1. xzb = bf16(xn @ W_in)   (8192x1024x256, bf16 MFMA, bf16 store)
  gemm_bf16<<<dim3(1024 / GTN, MROWS / GTM), 256, 0, stream>>>(
      xnb, Wib, xzb, MROWS, 1024, DIMC, 2, nullptr);

  // 2. fused: conv+SiLU (in LDS) ; dbcBC = (B|C) of u @ W_xproj ; dtu pack
  conv_xproj_dt<<<MROWS / 32, 256, 0, stream>>>(xzb, conv_w, conv_b,
                                                Wxpb, Wdtb, b_dt, dbcBC, dtu);

  // 3. chunked selective scan (3-pass form)
  dim3 gp13(BATCH, DI / 16, NC);
  dim3 gp2(BATCH, DI / 16);
  scan_pass1<<<gp13, 256, 0, stream>>>(dtu, dbcBC, A_log, hend, Ssum);
  scan_pass2<<<gp2, 256, 0, stream>>>(A_log, hend, Ssum, hin);
  scan_pass3<<<gp13, 256, 0, stream>>>(dtu, dbcBC, xzb, A_log, D_skip, hin, yb);

  // 4. out = yb @ W_out (transpose epilogue, +x residual)
  gemm_bf16<<<dim3(DIMC / GTN, MROWS / GTM), 256, 0, stream>>>(
      yb, Wob, out, MROWS, DIMC, DI, 1, x);
}

// Round 14
// 190.168 us; speedup vs baseline: 1.0122x; 1.0122x over previous
//
#include <hip/hip_runtime.h>
#include <hip/hip_bf16.h>
#include <math.h>

// Problem constants
#define DIMC   256      // DIM
#define DI     512      // D_INNER
#define DS     16       // D_STATE
#define DTR    16       // DT_RANK
#define NX     48       // DT_RANK + 2*D_STATE
#define BATCH  8
#define LSEQ   1024     // H*W
#define MROWS  8192     // BATCH*LSEQ
#define CHUNK  64
#define NC     (LSEQ / CHUNK)   // 16 chunks

typedef __attribute__((ext_vector_type(8))) short short8;
typedef __attribute__((ext_vector_type(4))) float f32x4;

__device__ __forceinline__ unsigned short f2bf(float v) {
  __hip_bfloat16 h = __float2bfloat16(v);
  return *reinterpret_cast<unsigned short*>(&h);
}
__device__ __forceinline__ float bf2f(unsigned short u) {
  return __int_as_float(((int)u) << 16);
}

// Async global->LDS, 16B per lane. lds base must be wave-uniform; HW writes
// lane i's 16B to ldsbase + i*16 (m97 pattern).
__device__ __forceinline__ void load_lds16(const void* g, void* l) {
  __builtin_amdgcn_global_load_lds(
      (const __attribute__((address_space(1))) unsigned int*)g,
      (__attribute__((address_space(3))) unsigned int*)l, 16, 0, 0);
}

// Sum across the 16-lane group using DPP only (zero DS ops).
__device__ __forceinline__ float dpp_sum16(float v) {
  float t;
  t = __int_as_float(__builtin_amdgcn_mov_dpp(__float_as_int(v), 0xB1,  0xF, 0xF, true)); v += t; // ^1
  t = __int_as_float(__builtin_amdgcn_mov_dpp(__float_as_int(v), 0x4E,  0xF, 0xF, true)); v += t; // ^2
  t = __int_as_float(__builtin_amdgcn_mov_dpp(__float_as_int(v), 0x141, 0xF, 0xF, true)); v += t; // ^7 (row_half_mirror)
  t = __int_as_float(__builtin_amdgcn_mov_dpp(__float_as_int(v), 0x140, 0xF, 0xF, true)); v += t; // ^15 (row_mirror)
  return v;
}

// ---------------------------------------------------------------------------
// Prologue: weight prep + LayerNorm in ONE launch (branch on blockIdx.x).
__global__ __launch_bounds__(256) void prologue(const float* __restrict__ W_in,
                                                const float* __restrict__ W_out,
                                                const float* __restrict__ W_xproj,
                                                const float* __restrict__ W_dt,
                                                const float* __restrict__ x,
                                                const float* __restrict__ gamma,
                                                const float* __restrict__ beta,
                                                unsigned short* __restrict__ Wib,
                                                unsigned short* __restrict__ Wob,
                                                unsigned short* __restrict__ Wxpb,
                                                unsigned short* __restrict__ Wdtb,
                                                unsigned short* __restrict__ xnb) {
  __shared__ float sx[DIMC][67];
  __shared__ float smean[64], srs[64];
  const int blk = blockIdx.x, tid = threadIdx.x;
  if (blk < 384) {
    float (*t)[67] = sx;
    const float* W; unsigned short* Wt; int K, N, bx, by;
    if (blk < 256) { W = W_in;  Wt = Wib; K = DIMC; N = 1024; bx = blk & 31; by = blk >> 5; }
    else           { W = W_out; Wt = Wob; K = DI;   N = DIMC; bx = (blk - 256) & 7; by = (blk - 256) >> 3; }
    int n0 = bx * 32, k0 = by * 32;
    int tx = tid & 31, ty = tid >> 5;
    for (int i = ty; i < 32; i += 8) t[i][tx] = W[(size_t)(k0 + i) * N + n0 + tx];
    __syncthreads();
    for (int i = ty; i < 32; i += 8)
      Wt[(size_t)(n0 + i) * K + k0 + tx] = f2bf(t[tx][i]);
    return;
  }
  if (blk < 512) {
    int idx = (blk - 384) * 256 + tid;   // < 64*512
    int n = idx >> 9, k = idx & 511;
    Wxpb[idx] = (n < NX) ? f2bf(W_xproj[(size_t)k * NX + n]) : (unsigned short)0;
    return;
  }
  if (blk < 576) {
    int idx = (blk - 512) * 256 + tid;   // < 512*32
    int n = idx >> 5, k = idx & 31;
    Wdtb[idx] = (k < DTR) ? f2bf(W_dt[(size_t)k * DI + n]) : (unsigned short)0;
    return;
  }
  // ---- LayerNorm ----
  const int lb = blk - 576;
  const int b = lb >> 4, l0 = (lb & 15) * 64;
  {
    const int cbase = tid >> 2;
    const int lp = (tid & 3) * 16;
#pragma unroll
    for (int cg = 0; cg < 4; ++cg) {
      const int c = cg * 64 + cbase;
      const float* p = x + ((size_t)b * DIMC + c) * LSEQ + l0 + lp;
#pragma unroll
      for (int q = 0; q < 4; ++q) {
        float4 v = *(const float4*)(p + q * 4);
        sx[c][lp + q * 4 + 0] = v.x;
        sx[c][lp + q * 4 + 1] = v.y;
        sx[c][lp + q * 4 + 2] = v.z;
        sx[c][lp + q * 4 + 3] = v.w;
      }
    }
  }
  __syncthreads();
  {
    const int lane = tid & 63, w = tid >> 6;
    const int l = (w << 4) + (lane & 15);
    const int quad = lane >> 4;
    float sum = 0.f, sq = 0.f;
#pragma unroll 8
    for (int cc = 0; cc < 64; ++cc) {
      float v = sx[quad * 64 + cc][l];
      sum += v; sq += v * v;
    }
    sum += __shfl_xor(sum, 16); sq += __shfl_xor(sq, 16);
    sum += __shfl_xor(sum, 32); sq += __shfl_xor(sq, 32);
    if (quad == 0) {
      float mean = sum * (1.f / 256.f);
      float var  = sq * (1.f / 256.f) - mean * mean;
      smean[l] = mean; srs[l] = rsqrtf(var + 1e-5f);
    }
  }
  __syncthreads();
  {
    const float gg = gamma[tid], bb = beta[tid];
    const size_t base = ((size_t)b * LSEQ + l0) * DIMC + tid;
#pragma unroll 4
    for (int ll = 0; ll < 64; ++ll) {
      float v = (sx[tid][ll] - smean[ll]) * srs[ll] * gg + bb;
      xnb[base + (size_t)ll * DIMC] = f2bf(v);
    }
  }
}

// ---------------------------------------------------------------------------
// bf16 MFMA GEMM: C = A(bf16 [M][K]) * Bt(bf16 [N][K])^T.
// Staging via global_load_lds width=16 (As/Bs are pad-free, LDS offset = id*16).
// mode 1: f32 out[b*DIMC*LSEQ + n*LSEQ + l] = acc + X  (transpose + residual)
// mode 2: bf16 C row-major [M][N]
#define GTM 128
#define GTN 64
#define GBK 32
__global__ __launch_bounds__(256) void gemm_bf16(const unsigned short* __restrict__ A,
                                                 const unsigned short* __restrict__ Bt,
                                                 void* __restrict__ Cout,
                                                 int M, int N, int K, int mode,
                                                 const float* __restrict__ X) {
  __shared__ unsigned short As[GTM][GBK];
  __shared__ unsigned short Bs[GTN][GBK];
  const int tid = threadIdx.x;
  const int lane = tid & 63, wave = tid >> 6;
  const int wm = wave >> 1, wn = wave & 1;
  const int quad = lane >> 4, l16 = lane & 15;
  const int m0 = blockIdx.y * GTM, n0 = blockIdx.x * GTN;

  f32x4 acc[4][2];
#pragma unroll
  for (int i = 0; i < 4; ++i)
#pragma unroll
    for (int j = 0; j < 2; ++j) acc[i][j] = (f32x4){0.f, 0.f, 0.f, 0.f};

  for (int k0 = 0; k0 < K; k0 += GBK) {
    // A tile: ids 0..511 (2/thread), 16B each; LDS offset = id*16 (contiguous).
#pragma unroll
    for (int q = 0; q < 2; ++q) {
      int id = q * 256 + tid;
      int row = id >> 2, c = id & 3;
      load_lds16(A + (size_t)(m0 + row) * K + k0 + c * 8,
                 (char*)&As[0][0] + (size_t)(q * 256 + wave * 64) * 16);
    }
    // B tile: ids 0..255 (1/thread).
    {
      int row = tid >> 2, c = tid & 3;
      load_lds16(Bt + (size_t)(n0 + row) * K + k0 + c * 8,
                 (char*)&Bs[0][0] + (size_t)(wave * 64) * 16);
    }
    __syncthreads();   // drains vmcnt before LDS reads
    short8 af[4], bfrag[2];
#pragma unroll
    for (int i = 0; i < 4; ++i)
      af[i] = *(const short8*)&As[wm * 64 + i * 16 + l16][quad * 8];
#pragma unroll
    for (int j = 0; j < 2; ++j)
      bfrag[j] = *(const short8*)&Bs[wn * 32 + j * 16 + l16][quad * 8];
#pragma unroll
    for (int i = 0; i < 4; ++i)
#pragma unroll
      for (int j = 0; j < 2; ++j)
        acc[i][j] = __builtin_amdgcn_mfma_f32_16x16x32_bf16(af[i], bfrag[j], acc[i][j], 0, 0, 0);
    __syncthreads();
  }

  if (mode == 2) {
    unsigned short* Cb = (unsigned short*)Cout;
#pragma unroll
    for (int i = 0; i < 4; ++i) {
      int rowb = wm * 64 + i * 16 + quad * 4;
#pragma unroll
      for (int j = 0; j < 2; ++j) {
        int n = n0 + wn * 32 + j * 16 + l16;
#pragma unroll
        for (int r = 0; r < 4; ++r)
          Cb[(size_t)(m0 + rowb + r) * N + n] = f2bf(acc[i][j][r]);
      }
    }
  } else {
    float* C = (float*)Cout;
#pragma unroll
    for (int i = 0; i < 4; ++i) {
      int m = m0 + wm * 64 + i * 16 + quad * 4;
      int b = m >> 10, l = m & 1023;
#pragma unroll
      for (int j = 0; j < 2; ++j) {
        int n = n0 + wn * 32 + j * 16 + l16;
        size_t o = (size_t)b * (DIMC * LSEQ) + (size_t)n * LSEQ + l;
        f32x4 xv = *(const f32x4*)(X + o);
        f32x4 rv = acc[i][j] + xv;
        *(f32x4*)(C + o) = rv;
      }
    }
  }
}

// ---------------------------------------------------------------------------
// Fused conv + SiLU + xproj + dt (MFMA). m-tile 32, grid 256.
// (VGPR staging kept: Bs needs +8 pad, incompatible with global_load_lds.)
__global__ __launch_bounds__(256) void conv_xproj_dt(
    const unsigned short* __restrict__ xzb,
    const float* __restrict__ conv_w,
    const float* __restrict__ conv_b,
    const unsigned short* __restrict__ Wxpb,
    const unsigned short* __restrict__ Wdtb,
    const float* __restrict__ b_dt,
    float* __restrict__ dbcBC,
    unsigned int* __restrict__ dtu) {
  __shared__ unsigned short Bs[64][512 + 8];
  __shared__ unsigned short sxz[35][512];
  __shared__ unsigned short su[32][512 + 8];
  __shared__ unsigned short sdbc[32][40];
  const int m0 = blockIdx.x * 32;
  const int l0 = m0 & 1023;
  const int tid = threadIdx.x, lane = tid & 63, w = tid >> 6;
  const int quad = lane >> 4, l16 = lane & 15;

  // Stage Wxpb (64x512) and the xz u-half tile with halo.
#pragma unroll
  for (int q = 0; q < 16; ++q) {
    int id = q * 256 + tid;
    int row = id >> 6, c8 = id & 63;
    *(uint4*)&Bs[row][c8 * 8] = *(const uint4*)(Wxpb + (size_t)row * 512 + c8 * 8);
  }
#pragma unroll
  for (int q = 0; q < 9; ++q) {
    int id = q * 256 + tid;           // < 35*64 = 2240 chunks
    if (id < 35 * 64) {
      int rr = id >> 6, c8 = id & 63;
      uint4 v; v.x = 0u; v.y = 0u; v.z = 0u; v.w = 0u;
      if (l0 - 3 + rr >= 0)
        v = *(const uint4*)(xzb + (size_t)(m0 - 3 + rr) * 1024 + c8 * 8);
      *(uint4*)&sxz[rr][c8 * 8] = v;
    }
  }
  __syncthreads();

  // conv(k=4) + bias + SiLU -> su (each thread 64 outputs, coalesced in c).
#pragma unroll 4
  for (int q = 0; q < 64; ++q) {
    int idx = q * 256 + tid;
    int r = idx >> 9, c = idx & 511;
    float4 wv = *(const float4*)(conv_w + c * 4);
    float acc = conv_b[c];
    acc = fmaf(bf2f(sxz[r + 0][c]), wv.x, acc);
    acc = fmaf(bf2f(sxz[r + 1][c]), wv.y, acc);
    acc = fmaf(bf2f(sxz[r + 2][c]), wv.z, acc);
    acc = fmaf(bf2f(sxz[r + 3][c]), wv.w, acc);
    float u = acc / (1.f + __expf(-acc));
    su[r][c] = f2bf(u);
  }
  __syncthreads();

  // xproj MFMA: A-frags straight from su.
  f32x4 acc[2];
  acc[0] = (f32x4){0.f, 0.f, 0.f, 0.f};
  acc[1] = (f32x4){0.f, 0.f, 0.f, 0.f};
#pragma unroll 4
  for (int k0 = 0; k0 < 512; k0 += 32) {
    short8 af0 = *(const short8*)&su[l16][k0 + quad * 8];
    short8 af1 = *(const short8*)&su[16 + l16][k0 + quad * 8];
    short8 bf  = *(const short8*)&Bs[w * 16 + l16][k0 + quad * 8];
    acc[0] = __builtin_amdgcn_mfma_f32_16x16x32_bf16(af0, bf, acc[0], 0, 0, 0);
    acc[1] = __builtin_amdgcn_mfma_f32_16x16x32_bf16(af1, bf, acc[1], 0, 0, 0);
  }
  // Persist only B (n=16..31) and C (n=32..47) columns.
  if (w == 1 || w == 2) {
#pragma unroll
    for (int i = 0; i < 2; ++i)
#pragma unroll
      for (int r = 0; r < 4; ++r)
        dbcBC[(size_t)(m0 + i * 16 + quad * 4 + r) * 32 + (w - 1) * 16 + l16] = acc[i][r];
  }
  if (w < 2) {
#pragma unroll
    for (int i = 0; i < 2; ++i)
#pragma unroll
      for (int r = 0; r < 4; ++r)
        sdbc[i * 16 + quad * 4 + r][w * 16 + l16] = f2bf(acc[i][r]);
  }
  __syncthreads();

  // dt MFMA + softplus + dtu pack (u pulled from su).
  short8 af0 = *(const short8*)&sdbc[l16][quad * 8];
  short8 af1 = *(const short8*)&sdbc[16 + l16][quad * 8];
#pragma unroll
  for (int jn = 0; jn < 8; ++jn) {
    const int n0 = w * 128 + jn * 16;
    short8 bf = *(const short8*)(Wdtb + (size_t)(n0 + l16) * 32 + quad * 8);
    f32x4 a0 = (f32x4){0.f, 0.f, 0.f, 0.f}, a1 = a0;
    a0 = __builtin_amdgcn_mfma_f32_16x16x32_bf16(af0, bf, a0, 0, 0, 0);
    a1 = __builtin_amdgcn_mfma_f32_16x16x32_bf16(af1, bf, a1, 0, 0, 0);
    const float bd = b_dt[n0 + l16];
#pragma unroll
    for (int r = 0; r < 4; ++r) {
      int lr0 = quad * 4 + r;
      int lr1 = lr0 + 16;
      float v = a0[r] + bd;
      float sp = (v > 20.f) ? v : log1pf(__expf(v));
      unsigned int u0 = (unsigned int)su[lr0][n0 + l16];
      dtu[(size_t)(m0 + lr0) * DI + n0 + l16] = u0 | ((unsigned int)f2bf(sp) << 16);
      float v2 = a1[r] + bd;
      float sp2 = (v2 > 20.f) ? v2 : log1pf(__expf(v2));
      unsigned int u1 = (unsigned int)su[lr1][n0 + l16];
      dtu[(size_t)(m0 + lr1) * DI + n0 + l16] = u1 | ((unsigned int)f2bf(sp2) << 16);
    }
  }
}

// ---------------------------------------------------------------------------
// Chunked selective scan, (d,s) LDS-staged layout.
// Pass 1: local scan from h=0 -> hend, sum dt. Grid (BATCH, 32, NC).
__global__ __launch_bounds__(256) void scan_pass1(const unsigned int* __restrict__ dtu,
                                                  const float* __restrict__ dbcBC,
                                                  const float* __restrict__ A_log,
                                                  float* __restrict__ hend,
                                                  float* __restrict__ Ssum) {
  const int bb = blockIdx.x, dblk = blockIdx.y, cc = blockIdx.z;
  const int tid = threadIdx.x;
  const int di = tid >> 4, s = tid & 15;
  const int d = dblk * 16 + di;
  const float Ads = -__expf(A_log[d * DS + s]);

  __shared__ float2 sdu[CHUNK][18];   // (dt, u); pad -> <=2-way on b128 writes
  __shared__ float  sB[CHUNK][17];
  {
    const int t0 = cc * CHUNK;
    int lin = tid * 4;                 // 4 elems per thread
    int tt = lin >> 4, dd = lin & 15;  // dd in {0,4,8,12}
    size_t m = (size_t)bb * LSEQ + t0 + tt;
    uint4 du4 = *(const uint4*)(dtu + m * DI + dblk * 16 + dd);
    f32x4 a, b2;
    a[0]  = bf2f((unsigned short)(du4.x >> 16)); a[1]  = bf2f((unsigned short)(du4.x & 0xffff));
    a[2]  = bf2f((unsigned short)(du4.y >> 16)); a[3]  = bf2f((unsigned short)(du4.y & 0xffff));
    b2[0] = bf2f((unsigned short)(du4.z >> 16)); b2[1] = bf2f((unsigned short)(du4.z & 0xffff));
    b2[2] = bf2f((unsigned short)(du4.w >> 16)); b2[3] = bf2f((unsigned short)(du4.w & 0xffff));
    *(f32x4*)&sdu[tt][dd]     = a;
    *(f32x4*)&sdu[tt][dd + 2] = b2;
    f32x4 Bv = *(const f32x4*)(dbcBC + m * 32 + dd);
    *(f32x4*)&sB[tt][dd] = Bv;
  }
  __syncthreads();
  float h = 0.f, dtsum = 0.f;
#pragma unroll 4
  for (int tt = 0; tt < CHUNK; ++tt) {
    float2 du = sdu[tt][di];
    float Bv  = sB[tt][s];
    h = fmaf(__expf(du.x * Ads), h, du.x * du.y * Bv);
    dtsum += du.x;
  }
  size_t ci = ((size_t)(bb * NC + cc) * DI + d);
  hend[ci * DS + s] = h;
  if (s == 0) Ssum[ci] = dtsum;
}

// Pass 2: sequential combine over chunks -> h_in per chunk. (tiny, 256 blocks)
__global__ __launch_bounds__(256) void scan_pass2(const float* __restrict__ A_log,
                                                  const float* __restrict__ hend,
                                                  const float* __restrict__ Ssum,
                                                  float* __restrict__ hin) {
  const int bb = blockIdx.x, dblk = blockIdx.y;
  const int tid = threadIdx.x;
  const int di = tid >> 4, s = tid & 15;
  const int d = dblk * 16 + di;
  const float Ads = -__expf(A_log[d * DS + s]);
  float h = 0.f;
  for (int cc = 0; cc < NC; ++cc) {
    size_t ci = ((size_t)(bb * NC + cc) * DI + d);
    hin[ci * DS + s] = h;
    h = fmaf(__expf(Ads * Ssum[ci]), h, hend[ci * DS + s]);
  }
}

// Pass 3: re-run each chunk from true h_in, fused gate epilogue -> yb (bf16).
__global__ __launch_bounds__(256) void scan_pass3(const unsigned int* __restrict__ dtu,
                                                  const float* __restrict__ dbcBC,
                                                  const unsigned short* __restrict__ xzb,
                                                  const float* __restrict__ A_log,
                                                  const float* __restrict__ D_skip,
                                                  const float* __restrict__ hin,
                                                  unsigned short* __restrict__ yb) {
  const int bb = blockIdx.x, dblk = blockIdx.y, cc = blockIdx.z;
  const int tid = threadIdx.x;
  const int di = tid >> 4, s = tid & 15;
  const int d = dblk * 16 + di;
  const float Ads = -__expf(A_log[d * DS + s]);

  __shared__ float2 sdu[CHUNK][18];   // (dt, u)
  __shared__ float2 sBC[CHUNK][18];   // (B, C)
  __shared__ float  sy[CHUNK][16];
  const int t0 = cc * CHUNK;
  const size_t mbase = (size_t)bb * LSEQ + t0;
  {
    int lin = tid * 4;
    int tt = lin >> 4, dd = lin & 15;   // dd in {0,4,8,12}
    size_t m = mbase + tt;
    uint4 du4 = *(const uint4*)(dtu + m * DI + dblk * 16 + dd);
    f32x4 a, b2;
    a[0]  = bf2f((unsigned short)(du4.x >> 16)); a[1]  = bf2f((unsigned short)(du4.x & 0xffff));
    a[2]  = bf2f((unsigned short)(du4.y >> 16)); a[3]  = bf2f((unsigned short)(du4.y & 0xffff));
    b2[0] = bf2f((unsigned short)(du4.z >> 16)); b2[1] = bf2f((unsigned short)(du4.z & 0xffff));
    b2[2] = bf2f((unsigned short)(du4.w >> 16)); b2[3] = bf2f((unsigned short)(du4.w & 0xffff));
    *(f32x4*)&sdu[tt][dd]     = a;
    *(f32x4*)&sdu[tt][dd + 2] = b2;
    f32x4 Bv = *(const f32x4*)(dbcBC + m * 32 + dd);
    f32x4 Cv = *(const f32x4*)(dbcBC + m * 32 + 16 + dd);
    f32x4 p0, p1;
    p0[0] = Bv[0]; p0[1] = Cv[0]; p0[2] = Bv[1]; p0[3] = Cv[1];
    p1[0] = Bv[2]; p1[1] = Cv[2]; p1[2] = Bv[3]; p1[3] = Cv[3];
    *(f32x4*)&sBC[tt][dd]     = p0;
    *(f32x4*)&sBC[tt][dd + 2] = p1;
  }
  __syncthreads();
  float h = hin[((size_t)(bb * NC + cc) * DI + d) * DS + s];
#pragma unroll 4
  for (int tt = 0; tt < CHUNK; ++tt) {
    float2 du = sdu[tt][di];
    float2 bc = sBC[tt][s];
    h = fmaf(__expf(du.x * Ads), h, du.x * du.y * bc.x);
    float v = dpp_sum16(h * bc.y);
    if (s == 0) sy[tt][di] = v;
  }
  __syncthreads();
#pragma unroll
  for (int q = 0; q < 4; ++q) {
    int lin = q * 256 + tid;
    int tt = lin >> 4, dd = lin & 15;
    size_t m = mbase + tt;
    float z = bf2f(xzb[m * 1024 + DI + dblk * 16 + dd]);   // direct global, coalesced
    float yv = sy[tt][dd] + sdu[tt][dd].y * D_skip[dblk * 16 + dd];
    yv *= z / (1.f + __expf(-z));
    yb[m * DI + dblk * 16 + dd] = f2bf(yv);
  }
}

// ---------------------------------------------------------------------------
extern "C" void kernel_launch(void* const* d_in, const int* in_sizes, int n_in,
                              void* d_out, int out_size, void* d_ws, size_t ws_size,
                              hipStream_t stream) {
  const float* x       = (const float*)d_in[0];
  const float* ln_g    = (const float*)d_in[1];
  const float* ln_b    = (const float*)d_in[2];
  const float* W_in    = (const float*)d_in[3];
  const float* conv_w  = (const float*)d_in[4];
  const float* conv_b  = (const float*)d_in[5];
  const float* W_xproj = (const float*)d_in[6];
  const float* W_dt    = (const float*)d_in[7];
  const float* b_dt    = (const float*)d_in[8];
  const float* A_log   = (const float*)d_in[9];
  const float* D_skip  = (const float*)d_in[10];
  const float* W_out   = (const float*)d_in[11];
  float* out = (float*)d_out;

  // Workspace layout
  float* ws    = (float*)d_ws;
  float* dbcBC = ws;                                    //   262,144 f
  float* hend  = dbcBC + (size_t)MROWS * 32;            // 1,048,576 f
  float* hin   = hend + (size_t)BATCH * NC * DI * DS;   // 1,048,576 f
  float* Ssum  = hin  + (size_t)BATCH * NC * DI * DS;   //    65,536 f
  unsigned int* dtu = (unsigned int*)(Ssum + (size_t)BATCH * NC * DI); // 4,194,304 u32
  unsigned short* xzb  = (unsigned short*)(dtu + (size_t)MROWS * DI); // 8,388,608 us
  unsigned short* yb   = xzb + (size_t)MROWS * 1024;    // 4,194,304 us
  unsigned short* xnb  = yb;   // alias: xnb dead before pass3 writes yb
  unsigned short* Wib  = yb  + (size_t)MROWS * DI;      // 262,144 us
  unsigned short* Wob  = Wib + (size_t)DIMC * 1024;     // 131,072 us
  unsigned short* Wxpb = Wob + (size_t)DI * DIMC;       //  32,768 us
  unsigned short* Wdtb = Wxpb + (size_t)64 * 512;       //  16,384 us

  // 0. prologue: weight prep + LayerNorm, one launch
  prologue<<<704, 256, 0, stream>>>(W_in, W_out, W_xproj, W_dt, x, ln_g, ln_b,
                                    Wib, Wob, Wxpb, Wdtb, xnb);

  // 1. xzb = bf16(xn @ W_in)   (8192x1024x256, bf16 MFMA, bf16 store)
  gemm_bf16<<<dim3(1024 / GTN, MROWS / GTM), 256, 0, stream>>>(
      xnb, Wib, xzb, MROWS, 1024, DIMC, 2, nullptr);

  // 2. fused: conv+SiLU (in LDS) ; dbcBC = (B|C) of u @ W_xproj ; dtu pack
  conv_xproj_dt<<<MROWS / 32, 256, 0, stream>>>(xzb, conv_w, conv_b,
                                                Wxpb, Wdtb, b_dt, dbcBC, dtu);

  // 3. chunked selective scan (3-pass form)
  dim3 gp13(BATCH, DI / 16, NC);
  dim3 gp2(BATCH, DI / 16);
  scan_pass1<<<gp13, 256, 0, stream>>>(dtu, dbcBC, A_log, hend, Ssum);
  scan_pass2<<<gp2, 256, 0, stream>>>(A_log, hend, Ssum, hin);
  scan_pass3<<<gp13, 256, 0, stream>>>(dtu, dbcBC, xzb, A_log, D_skip, hin, yb);

  // 4. out = yb @ W_out (transpose epilogue, +x residual)
  gemm_bf16<<<dim3(DIMC / GTN, MROWS / GTM), 256, 0, stream>>>(
      yb, Wob, out, MROWS, DIMC, DI, 1, x);
}